// Round 8
// baseline (3380.108 us; speedup 1.0000x reference)
//
#include <hip/hip_runtime.h>
#include <math.h>

#define N_NODES 11616
#define NROWPAD 11776   // 92*128, padded rows for xh/xl
#define NHID    512
#define EDGES   371712
#define S0 4278
#define S1 2081
#define S2 5257
#define F0 3066
#define F1 2081
#define F2 5257
#define NBLK 91   // ceil(11616/128)
#define FC_KS 4  // split-K factor for input FCs

typedef __attribute__((ext_vector_type(8))) short bf16x8;
typedef __attribute__((ext_vector_type(4))) float f32x4;

#define GL2LDS(g, l) __builtin_amdgcn_global_load_lds(                         \
    (const __attribute__((address_space(1))) unsigned int*)(g),                \
    (__attribute__((address_space(3))) unsigned int*)(l), 16, 0, 0)

__device__ __forceinline__ int slot_of(int row, int kg)
{
    return row * 4 + (kg ^ ((row >> 1) & 3));
}

// ---------------- init ----------------
__global__ void k_init(double* __restrict__ accum, int* __restrict__ indeg,
                       int* __restrict__ cursor)
{
    int i = blockIdx.x * blockDim.x + threadIdx.x;
    if (i < 2) accum[i] = 0.0;
    if (i < N_NODES) { indeg[i] = 0; cursor[i] = 0; }
}

__global__ void k_padzero(short* __restrict__ xh, short* __restrict__ xl)
{
    int i = blockIdx.x * blockDim.x + threadIdx.x;
    const int base  = N_NODES * NHID;
    const int total = (NROWPAD - N_NODES) * NHID;
    if (i < total) { xh[base + i] = 0; xl[base + i] = 0; }
}

// ---------------- CSR build ----------------
__global__ void k_count(const int* __restrict__ dst, int* __restrict__ indeg)
{
    int e = blockIdx.x * blockDim.x + threadIdx.x;
    if (e < EDGES) atomicAdd(&indeg[dst[e]], 1);
}

__global__ void k_scan(const int* __restrict__ indeg, int* __restrict__ rowptr)
{
    __shared__ int part[256];
    const int t = threadIdx.x;
    const int chunk = (N_NODES + 255) / 256;
    const int base = t * chunk;
    int s = 0;
    for (int i = 0; i < chunk; ++i) {
        int idx = base + i;
        if (idx < N_NODES) s += indeg[idx];
    }
    part[t] = s;
    __syncthreads();
    if (t == 0) for (int i = 1; i < 256; ++i) part[i] += part[i - 1];
    __syncthreads();
    int run = (t == 0) ? 0 : part[t - 1];
    for (int i = 0; i < chunk; ++i) {
        int idx = base + i;
        if (idx < N_NODES) { rowptr[idx] = run; run += indeg[idx]; }
    }
    if (t == 0) rowptr[N_NODES] = part[255];
}

__global__ void k_fill(const int* __restrict__ src, const int* __restrict__ dst,
                       const float* __restrict__ ew, const int* __restrict__ rowptr,
                       int* __restrict__ cursor, int* __restrict__ csrc,
                       float* __restrict__ cw)
{
    int e = blockIdx.x * blockDim.x + threadIdx.x;
    if (e >= EDGES) return;
    int d = dst[e];
    int pos = rowptr[d] + atomicAdd(&cursor[d], 1);
    csrc[pos] = src[e];
    cw[pos]   = ew[e];
}

// ---------------- bf16 hi/lo split ----------------
__device__ __forceinline__ void split_bf16(float f, short& hi, short& lo)
{
    unsigned u  = __float_as_uint(f);
    unsigned hr = (u + 0x7FFFu + ((u >> 16) & 1u)) & 0xFFFF0000u;
    float    fh = __uint_as_float(hr);
    float    fl = f - fh;
    unsigned ul = __float_as_uint(fl);
    unsigned lr = ul + 0x7FFFu + ((ul >> 16) & 1u);
    hi = (short)(hr >> 16);
    lo = (short)(lr >> 16);
}

// elementwise split with row+col zero-padding: in[R][C] fp32 -> oh/ol[Rpad][Cpad]
__global__ void k_splitpad(const float* __restrict__ in, short* __restrict__ oh,
                           short* __restrict__ ol, int R, int C, int Cpad)
{
    const int c = blockIdx.x * 256 + threadIdx.x;
    const int r = blockIdx.y;
    if (c >= Cpad) return;
    float f = (r < R && c < C) ? in[(long)r * C + c] : 0.f;
    short h, l;
    split_bf16(f, h, l);
    oh[(long)r * Cpad + c] = h;
    ol[(long)r * Cpad + c] = l;
}

// transpose + split: in[R][C] fp32 -> oh/ol[Cpad][Rpad] bf16 (zero pads both dims)
__global__ void k_tsplit(const float* __restrict__ in, short* __restrict__ oh,
                         short* __restrict__ ol, int R, int C, int Rpad, int Cpad)
{
    __shared__ float tile[32][33];
    const int cb = blockIdx.x * 32, rb = blockIdx.y * 32;
    const int tx = threadIdx.x, ty = threadIdx.y;   // 32 x 8
    #pragma unroll
    for (int i = ty; i < 32; i += 8) {
        int r = rb + i, c = cb + tx;
        tile[i][tx] = (r < R && c < C) ? in[(long)r * C + c] : 0.f;
    }
    __syncthreads();
    #pragma unroll
    for (int i = ty; i < 32; i += 8) {
        int row = cb + i, col = rb + tx;
        if (row < Cpad && col < Rpad) {
            short h, l;
            split_bf16(tile[tx][i], h, l);
            oh[(long)row * Rpad + col] = h;
            ol[(long)row * Rpad + col] = l;
        }
    }
}

// stage one 128x32 bf16 panel via global_load_lds (pre-swizzled source, linear dest)
__device__ __forceinline__ void stage_gl(const short* __restrict__ src, int ldk,
                                         int k0, short* ldsPanel, int lane)
{
    #pragma unroll
    for (int i = 0; i < 8; ++i) {
        int ci  = i * 64 + lane;
        int row = ci >> 2;
        int kgs = (ci & 3) ^ ((row >> 1) & 3);
        const short* g = src + (long)row * ldk + k0 + kgs * 8;
        GL2LDS(g, (char*)ldsPanel + i * 1024);
    }
}

// ---------------- GEMM: both operands pre-split bf16, gload_lds staged ----------------
__global__ __launch_bounds__(256, 3)
void k_gemm_bb(const short* __restrict__ Agh, const short* __restrict__ Agl,
               const short* __restrict__ Bgh, const short* __restrict__ Bgl,
               const float* __restrict__ bias, float* __restrict__ C,
               int M, int NN, int Kpad, int ldk)
{
    __shared__ short P[4][4096];
    const int t = threadIdx.x, lane = t & 63, w = t >> 6;
    const int rowBase = blockIdx.y * 128, colBase = blockIdx.x * 128;
    const int wm = (w >> 1) * 64, wn = (w & 1) * 64;
    const int kg = lane >> 4, fr = lane & 15;

    const short* srcs[4] = { Agh + (long)rowBase * ldk, Agl + (long)rowBase * ldk,
                             Bgh + (long)colBase * ldk, Bgl + (long)colBase * ldk };
    const short* mySrc = srcs[w];

    int offA[4], offB[4];
    #pragma unroll
    for (int f = 0; f < 4; ++f) {
        int rA = wm + f * 16 + fr, rB = wn + f * 16 + fr;
        offA[f] = slot_of(rA, kg) * 8;
        offB[f] = slot_of(rB, kg) * 8;
    }

    f32x4 acc[4][4];
    #pragma unroll
    for (int i = 0; i < 4; ++i)
        #pragma unroll
        for (int j = 0; j < 4; ++j)
            acc[i][j] = (f32x4){0.f, 0.f, 0.f, 0.f};

    for (int k0 = 0; k0 < Kpad; k0 += 32) {
        stage_gl(mySrc, ldk, k0, &P[w][0], lane);
        __syncthreads();
        bf16x8 ah[4], al[4], bh[4], bl[4];
        #pragma unroll
        for (int f = 0; f < 4; ++f) {
            ah[f] = *(const bf16x8*)&P[0][offA[f]];
            al[f] = *(const bf16x8*)&P[1][offA[f]];
            bh[f] = *(const bf16x8*)&P[2][offB[f]];
            bl[f] = *(const bf16x8*)&P[3][offB[f]];
        }
        #pragma unroll
        for (int i = 0; i < 4; ++i)
            #pragma unroll
            for (int j = 0; j < 4; ++j) {
                acc[i][j] = __builtin_amdgcn_mfma_f32_16x16x32_bf16(ah[i], bh[j], acc[i][j], 0, 0, 0);
                acc[i][j] = __builtin_amdgcn_mfma_f32_16x16x32_bf16(ah[i], bl[j], acc[i][j], 0, 0, 0);
                acc[i][j] = __builtin_amdgcn_mfma_f32_16x16x32_bf16(al[i], bh[j], acc[i][j], 0, 0, 0);
            }
        __syncthreads();
    }

    #pragma unroll
    for (int i = 0; i < 4; ++i) {
        #pragma unroll
        for (int q = 0; q < 4; ++q) {
            int r = rowBase + wm + i * 16 + kg * 4 + q;
            if (r >= M) continue;
            #pragma unroll
            for (int j = 0; j < 4; ++j) {
                int c = colBase + wn + j * 16 + fr;
                if (c < NN)
                    C[(long)r * NN + c] = acc[i][j][q] + (bias ? bias[c] : 0.f);
            }
        }
    }
}

// ---------------- split-K partial GEMM (for FCs): z-th K chunk -> fp32 partial ----------------
__global__ __launch_bounds__(256, 3)
void k_gemm_red(const short* __restrict__ Agh, const short* __restrict__ Agl,
                const short* __restrict__ Bgh, const short* __restrict__ Bgl,
                float* __restrict__ Cpart, int M, int ldk, int kChunk)
{
    __shared__ short P[4][4096];
    const int t = threadIdx.x, lane = t & 63, w = t >> 6;
    const int rowBase = blockIdx.y * 128, colBase = blockIdx.x * 128;
    const int z = blockIdx.z;
    const int wm = (w >> 1) * 64, wn = (w & 1) * 64;
    const int kg = lane >> 4, fr = lane & 15;

    const short* srcs[4] = { Agh + (long)rowBase * ldk, Agl + (long)rowBase * ldk,
                             Bgh + (long)colBase * ldk, Bgl + (long)colBase * ldk };
    const short* mySrc = srcs[w];

    int offA[4], offB[4];
    #pragma unroll
    for (int f = 0; f < 4; ++f) {
        int rA = wm + f * 16 + fr, rB = wn + f * 16 + fr;
        offA[f] = slot_of(rA, kg) * 8;
        offB[f] = slot_of(rB, kg) * 8;
    }

    f32x4 acc[4][4];
    #pragma unroll
    for (int i = 0; i < 4; ++i)
        #pragma unroll
        for (int j = 0; j < 4; ++j)
            acc[i][j] = (f32x4){0.f, 0.f, 0.f, 0.f};

    const int kEnd = z * kChunk + kChunk;
    for (int k0 = z * kChunk; k0 < kEnd; k0 += 32) {
        stage_gl(mySrc, ldk, k0, &P[w][0], lane);
        __syncthreads();
        bf16x8 ah[4], al[4], bh[4], bl[4];
        #pragma unroll
        for (int f = 0; f < 4; ++f) {
            ah[f] = *(const bf16x8*)&P[0][offA[f]];
            al[f] = *(const bf16x8*)&P[1][offA[f]];
            bh[f] = *(const bf16x8*)&P[2][offB[f]];
            bl[f] = *(const bf16x8*)&P[3][offB[f]];
        }
        #pragma unroll
        for (int i = 0; i < 4; ++i)
            #pragma unroll
            for (int j = 0; j < 4; ++j) {
                acc[i][j] = __builtin_amdgcn_mfma_f32_16x16x32_bf16(ah[i], bh[j], acc[i][j], 0, 0, 0);
                acc[i][j] = __builtin_amdgcn_mfma_f32_16x16x32_bf16(ah[i], bl[j], acc[i][j], 0, 0, 0);
                acc[i][j] = __builtin_amdgcn_mfma_f32_16x16x32_bf16(al[i], bh[j], acc[i][j], 0, 0, 0);
            }
        __syncthreads();
    }

    #pragma unroll
    for (int i = 0; i < 4; ++i) {
        #pragma unroll
        for (int q = 0; q < 4; ++q) {
            int r = rowBase + wm + i * 16 + kg * 4 + q;
            if (r >= M) continue;
            #pragma unroll
            for (int j = 0; j < 4; ++j) {
                int c = colBase + wn + j * 16 + fr;
                Cpart[((long)z * M + r) * NHID + c] = acc[i][j][q];
            }
        }
    }
}

// ---------------- FC reduce: sum FC_KS partials + bias, write fp32 + split ----------------
__global__ void k_fcreduce(const float* __restrict__ Cpart, const float* __restrict__ bias,
                           int M, float* __restrict__ xo, short* __restrict__ oh,
                           short* __restrict__ ol)
{
    const int r = blockIdx.x;
    const int c = threadIdx.x << 2;   // 128 threads
    float4 s = *reinterpret_cast<const float4*>(bias + c);
    #pragma unroll
    for (int z = 0; z < FC_KS; ++z) {
        const float4 p = *reinterpret_cast<const float4*>(Cpart + ((long)z * M + r) * NHID + c);
        s.x += p.x; s.y += p.y; s.z += p.z; s.w += p.w;
    }
    *reinterpret_cast<float4*>(xo + (long)r * NHID + c) = s;
    short4 h, l;
    split_bf16(s.x, h.x, l.x); split_bf16(s.y, h.y, l.y);
    split_bf16(s.z, h.z, l.z); split_bf16(s.w, h.w, l.w);
    *reinterpret_cast<short4*>(oh + (long)r * NHID + c) = h;
    *reinterpret_cast<short4*>(ol + (long)r * NHID + c) = l;
}

// ---------------- zloss: upper-triangle blocks of z = x x^T, fused loss ----------------
__global__ __launch_bounds__(256, 4)
void k_zloss(const short* __restrict__ xh, const short* __restrict__ xl,
             const float* __restrict__ adj, double* __restrict__ accum)
{
    __shared__ union {
        short P[4][4096];
        struct { float ztr[4][16][17]; float red[256]; } e;
    } U;
    const int t = threadIdx.x, lane = t & 63, w = t >> 6;

    int b = blockIdx.x, R = 0;
    while (b >= NBLK - R) { b -= NBLK - R; ++R; }
    const int Cb = R + b;
    const int rowBase = R * 128, colBase = Cb * 128;
    const int diag = (Cb == R);

    const int wm = (w >> 1) * 64, wn = (w & 1) * 64;
    const int kg = lane >> 4, fr = lane & 15;

    const short* srcs[4] = { xh + (long)rowBase * NHID, xl + (long)rowBase * NHID,
                             xh + (long)colBase * NHID, xl + (long)colBase * NHID };
    const short* mySrc = srcs[w];

    int offA[4], offB[4];
    #pragma unroll
    for (int f = 0; f < 4; ++f) {
        int rA = wm + f * 16 + fr, rB = wn + f * 16 + fr;
        offA[f] = slot_of(rA, kg) * 8;
        offB[f] = slot_of(rB, kg) * 8;
    }

    f32x4 acc[4][4];
    #pragma unroll
    for (int i = 0; i < 4; ++i)
        #pragma unroll
        for (int j = 0; j < 4; ++j)
            acc[i][j] = (f32x4){0.f, 0.f, 0.f, 0.f};

    for (int k0 = 0; k0 < NHID; k0 += 32) {
        stage_gl(mySrc, NHID, k0, &U.P[w][0], lane);
        __syncthreads();
        bf16x8 ah[4], al[4], bh[4], bl[4];
        #pragma unroll
        for (int f = 0; f < 4; ++f) {
            ah[f] = *(const bf16x8*)&U.P[0][offA[f]];
            al[f] = *(const bf16x8*)&U.P[1][offA[f]];
            bh[f] = *(const bf16x8*)&U.P[2][offB[f]];
            bl[f] = *(const bf16x8*)&U.P[3][offB[f]];
        }
        #pragma unroll
        for (int i = 0; i < 4; ++i)
            #pragma unroll
            for (int j = 0; j < 4; ++j) {
                acc[i][j] = __builtin_amdgcn_mfma_f32_16x16x32_bf16(ah[i], bh[j], acc[i][j], 0, 0, 0);
                acc[i][j] = __builtin_amdgcn_mfma_f32_16x16x32_bf16(ah[i], bl[j], acc[i][j], 0, 0, 0);
                acc[i][j] = __builtin_amdgcn_mfma_f32_16x16x32_bf16(al[i], bh[j], acc[i][j], 0, 0, 0);
            }
        __syncthreads();
    }

    // epilogue: LDS reused (union) for per-wave fragment transpose + reduction
    float local = 0.f;
    #pragma unroll
    for (int i = 0; i < 4; ++i) {
        #pragma unroll
        for (int j = 0; j < 4; ++j) {
            const int rbase = rowBase + wm + i * 16;
            const int cbase = colBase + wn + j * 16;
            if (!diag) {
                #pragma unroll
                for (int q = 0; q < 4; ++q)
                    U.e.ztr[w][kg * 4 + q][fr] = acc[i][j][q];
            }
            #pragma unroll
            for (int q = 0; q < 4; ++q) {
                float z  = acc[i][j][q];
                float sp = fmaxf(z, 0.f) + __logf(1.f + __expf(-fabsf(z)));
                int r = rbase + kg * 4 + q, c = cbase + fr;
                if (r < N_NODES && c < N_NODES) {
                    float a1 = adj[(long)r * N_NODES + c];
                    local += diag ? (sp - a1 * z) : (2.f * sp - a1 * z);
                }
            }
            if (!diag) {
                #pragma unroll
                for (int q = 0; q < 4; ++q) {
                    float zt = U.e.ztr[w][fr][kg * 4 + q];
                    int cc = cbase + kg * 4 + q;   // adj row
                    int rr = rbase + fr;           // adj col (contig per lane)
                    if (cc < N_NODES && rr < N_NODES)
                        local -= adj[(long)cc * N_NODES + rr] * zt;
                }
            }
        }
    }
    __syncthreads();
    U.e.red[t] = local;
    __syncthreads();
    for (int sft = 128; sft > 0; sft >>= 1) {
        if (t < sft) U.e.red[t] += U.e.red[t + sft];
        __syncthreads();
    }
    if (t == 0) atomicAdd(accum, (double)U.e.red[0]);
}

// ---------------- SpMM, L2-resident channel slices (8 x 64ch, slice-major grid) ----------------
__global__ void k_spmm(const float* __restrict__ y, const float* __restrict__ xold,
                       const int* __restrict__ rowptr, const int* __restrict__ csrc,
                       const float* __restrict__ cw, const float* __restrict__ bias,
                       int do_relu, float* __restrict__ xnew,
                       short* __restrict__ xh, short* __restrict__ xl)
{
    const int slice = blockIdx.x / (N_NODES / 4);   // 0..7, slice-major: one 3MB y-slice hot per XCD L2
    const int ng    = blockIdx.x % (N_NODES / 4);
    const int wv    = threadIdx.x >> 6;
    const int lane  = threadIdx.x & 63;
    const int n     = ng * 4 + wv;                  // 2904*4 == 11616 exactly
    const int c     = slice * 64 + lane;
    float s = 0.f;
    const int beg = rowptr[n], end = rowptr[n + 1];
    for (int e = beg; e < end; ++e) {
        int   sn = csrc[e];
        float wt = cw[e];
        s = fmaf(wt, y[(long)sn * NHID + c], s);
    }
    float o = s + bias[c];
    if (do_relu) o = fmaxf(o, 0.f);
    else         o += xold[(long)n * NHID + c];
    xnew[(long)n * NHID + c] = o;
    short h, l;
    split_bf16(o, h, l);
    xh[(long)n * NHID + c] = h;
    xl[(long)n * NHID + c] = l;
}

// ---------------- recon loss ----------------
__global__ void k_recon(const float* __restrict__ r0, const float* __restrict__ X0,
                        double* __restrict__ accum)
{
    const int row = blockIdx.x;
    const int t = threadIdx.x;   // 256
    float dot = 0.f, nr = 0.f, nf = 0.f;
    for (int c = t; c < F0; c += 256) {
        float a = r0[(long)row * F0 + c];
        float b = X0[(long)row * F0 + c];
        dot = fmaf(a, b, dot);
        nr  = fmaf(a, a, nr);
        nf  = fmaf(b, b, nf);
    }
    #pragma unroll
    for (int o = 32; o > 0; o >>= 1) {
        dot += __shfl_down(dot, o);
        nr  += __shfl_down(nr, o);
        nf  += __shfl_down(nf, o);
    }
    __shared__ float sd[3][4];
    const int lane = t & 63, wid = t >> 6;
    if (lane == 0) { sd[0][wid] = dot; sd[1][wid] = nr; sd[2][wid] = nf; }
    __syncthreads();
    if (t == 0) {
        float d = sd[0][0] + sd[0][1] + sd[0][2] + sd[0][3];
        float a = sd[1][0] + sd[1][1] + sd[1][2] + sd[1][3];
        float b = sd[2][0] + sd[2][1] + sd[2][2] + sd[2][3];
        float cosv = d / (fmaxf(sqrtf(a), 1e-12f) * fmaxf(sqrtf(b), 1e-12f));
        float v = 1.f - cosv;
        atomicAdd(accum + 1, (double)(v * v * v));
    }
}

__global__ void k_final(const double* __restrict__ accum, float* __restrict__ out)
{
    if (threadIdx.x == 0) {
        out[45082958] = (float)(accum[0] / ((double)N_NODES * (double)N_NODES));
        out[45082959] = (float)(accum[1] / (double)S0);
    }
}

extern "C" void kernel_launch(void* const* d_in, const int* in_sizes, int n_in,
                              void* d_out, int out_size, void* d_ws, size_t ws_size,
                              hipStream_t stream)
{
    const float* X0  = (const float*)d_in[0];
    const float* X1  = (const float*)d_in[1];
    const float* X2  = (const float*)d_in[2];
    const int*   src = (const int*)d_in[3];
    const int*   dst = (const int*)d_in[4];
    const float* ew  = (const float*)d_in[5];
    const float* adj = (const float*)d_in[6];
    const float* fcW[3]  = {(const float*)d_in[7],  (const float*)d_in[9],  (const float*)d_in[11]};
    const float* fcB[3]  = {(const float*)d_in[8],  (const float*)d_in[10], (const float*)d_in[12]};
    const float* encW = (const float*)d_in[13];
    const float* encB = (const float*)d_in[14];
    const float* decW = (const float*)d_in[15];
    const float* decB = (const float*)d_in[16];
    const float* outW[3] = {(const float*)d_in[17], (const float*)d_in[19], (const float*)d_in[21]};
    const float* outB[3] = {(const float*)d_in[18], (const float*)d_in[20], (const float*)d_in[22]};
    float* out = (float*)d_out;

    const int FD[3]     = {F0, F1, F2};
    const int FPAD[3]   = {(F0 + 127) & ~127, (F1 + 127) & ~127, (F2 + 127) & ~127}; // K pad (128-mult)
    const int SPAD[3]   = {(S0 + 127) & ~127, (S1 + 127) & ~127, (S2 + 127) & ~127}; // row pad
    const int SD[3]     = {S0, S1, S2};
    const float* XD[3]  = {X0, X1, X2};

    char* ws = (char*)d_ws;
    size_t off = 0;
    auto alloc = [&](size_t bytes) { void* p = ws + off; off += (bytes + 255) & ~(size_t)255; return p; };

    double* accum = (double*)alloc(16);
    const size_t XB = (size_t)N_NODES * NHID * sizeof(float);
    float* xbuf = (float*)alloc(XB);
    float* ybuf = (float*)alloc(XB);   // FC phase: aliased as split-K partial buffer
    float* xalt = (float*)alloc(XB);   // (cpart spans ybuf+xalt, 47.6MB >= 43.1MB needed)
    short* xh   = (short*)alloc((size_t)NROWPAD * NHID * 2);
    short* xl   = (short*)alloc((size_t)NROWPAD * NHID * 2);
    // X split staging (max over the 3 types); reused later for outW splits
    const size_t XSmax = (size_t)5376 * 5376;
    short* Xsh  = (short*)alloc(XSmax * 2);
    short* Xsl  = (short*)alloc(XSmax * 2);
    // fc weight split (max 512*5376)
    short* fcWh = (short*)alloc((size_t)NHID * 5376 * 2);
    short* fcWl = (short*)alloc((size_t)NHID * 5376 * 2);
    short* wTh  = (short*)alloc((size_t)8 * NHID * NHID * 2);
    short* wTl  = (short*)alloc((size_t)8 * NHID * NHID * 2);
    int* indeg  = (int*)alloc((size_t)N_NODES * 4);
    int* rowptr = (int*)alloc((size_t)(N_NODES + 1) * 4);
    int* cursor = (int*)alloc((size_t)N_NODES * 4);
    int* csrc   = (int*)alloc((size_t)EDGES * 4);
    float* cw   = (float*)alloc((size_t)EDGES * 4);

    float* cpart = ybuf;   // alias: free until first layer GEMM

    // ---- CSR build + pad zero ----
    k_init<<<dim3((N_NODES + 255) / 256), dim3(256), 0, stream>>>(accum, indeg, cursor);
    k_padzero<<<dim3(((NROWPAD - N_NODES) * NHID + 255) / 256), dim3(256), 0, stream>>>(xh, xl);
    k_count<<<dim3((EDGES + 255) / 256), dim3(256), 0, stream>>>(dst, indeg);
    k_scan<<<dim3(1), dim3(256), 0, stream>>>(indeg, rowptr);
    k_fill<<<dim3((EDGES + 255) / 256), dim3(256), 0, stream>>>(src, dst, ew, rowptr, cursor, csrc, cw);

    auto tgrid = [](int Cpad, int Rpad) { return dim3((unsigned)((Cpad + 31) / 32), (unsigned)((Rpad + 31) / 32)); };
    auto ggrid = [](int m, int nn) { return dim3((unsigned)((nn + 127) / 128), (unsigned)((m + 127) / 128)); };

    // ---- enc/dec weight transpose+split ----
    for (int i = 0; i < 4; ++i) {
        k_tsplit<<<tgrid(NHID, NHID), dim3(32, 8), 0, stream>>>(
            encW + (size_t)i * NHID * NHID, wTh + (size_t)i * NHID * NHID,
            wTl + (size_t)i * NHID * NHID, NHID, NHID, NHID, NHID);
        k_tsplit<<<tgrid(NHID, NHID), dim3(32, 8), 0, stream>>>(
            decW + (size_t)i * NHID * NHID, wTh + (size_t)(4 + i) * NHID * NHID,
            wTl + (size_t)(4 + i) * NHID * NHID, NHID, NHID, NHID, NHID);
    }

    // ---- input FCs via split-K ----
    {
        size_t rowoff = 0;
        for (int i = 0; i < 3; ++i) {
            k_splitpad<<<dim3((FPAD[i] + 255) / 256, SPAD[i]), dim3(256), 0, stream>>>(
                XD[i], Xsh, Xsl, SD[i], FD[i], FPAD[i]);
            k_tsplit<<<tgrid(NHID, FPAD[i]), dim3(32, 8), 0, stream>>>(
                fcW[i], fcWh, fcWl, FD[i], NHID, FPAD[i], NHID);
            k_gemm_red<<<dim3(NHID / 128, SPAD[i] / 128, FC_KS), dim3(256), 0, stream>>>(
                Xsh, Xsl, fcWh, fcWl, cpart, SD[i], FPAD[i], FPAD[i] / FC_KS);
            k_fcreduce<<<dim3(SD[i]), dim3(128), 0, stream>>>(
                cpart, fcB[i], SD[i], xbuf + rowoff * NHID,
                xh + rowoff * NHID, xl + rowoff * NHID);
            rowoff += SD[i];
        }
    }

    // ---- 8 GNN layers (split fused into spmm) ----
    float* x  = xbuf;
    float* xn = xalt;
    for (int phase = 0; phase < 2; ++phase) {
        const float* B = phase ? decB : encB;
        for (int i = 0; i < 4; ++i) {
            k_gemm_bb<<<ggrid(N_NODES, NHID), dim3(256), 0, stream>>>(
                xh, xl, wTh + (size_t)(phase * 4 + i) * NHID * NHID,
                wTl + (size_t)(phase * 4 + i) * NHID * NHID,
                nullptr, ybuf, N_NODES, NHID, NHID, NHID);
            k_spmm<<<dim3((N_NODES / 4) * 8), dim3(256), 0, stream>>>(
                ybuf, x, rowptr, csrc, cw, B + (size_t)i * NHID, (i == 0) ? 1 : 0,
                xn, xh, xl);
            float* tmp = x; x = xn; xn = tmp;
        }
    }

    // ---- outW transpose+split (into the now-free X staging region) ----
    short* oWh = Xsh;
    short* oWl = Xsl;
    {
        short *ph = oWh, *pl = oWl;
        for (int i = 0; i < 3; ++i) {
            int FDP = (FD[i] + 127) & ~127;
            k_tsplit<<<tgrid(FDP, NHID), dim3(32, 8), 0, stream>>>(
                outW[i], ph, pl, NHID, FD[i], NHID, FDP);
            ph += (size_t)FDP * NHID; pl += (size_t)FDP * NHID;
        }
    }

    // ---- output projections ----
    {
        short *ph = oWh, *pl = oWl;
        float* oo = out;
        size_t rowoff = 0;
        for (int i = 0; i < 3; ++i) {
            int FDP = (FD[i] + 127) & ~127;
            k_gemm_bb<<<ggrid(SD[i], FD[i]), dim3(256), 0, stream>>>(
                xh + rowoff * NHID, xl + rowoff * NHID, ph, pl, outB[i], oo,
                SD[i], FD[i], NHID, NHID);
            ph += (size_t)FDP * NHID; pl += (size_t)FDP * NHID;
            oo += (size_t)SD[i] * FD[i];
            rowoff += SD[i];
        }
    }

    // ---- losses ----
    k_zloss<<<dim3(NBLK * (NBLK + 1) / 2), dim3(256), 0, stream>>>(xh, xl, adj, accum);
    k_recon<<<dim3(S0), dim3(256), 0, stream>>>(out, X0, accum);
    k_final<<<dim3(1), dim3(64), 0, stream>>>(accum, out);
}

// Round 9
// 2291.369 us; speedup vs baseline: 1.4751x; 1.4751x over previous
//
#include <hip/hip_runtime.h>
#include <math.h>

#define N_NODES 11616
#define NROWPAD 11776   // 92*128, padded rows for xh/xl
#define NHID    512
#define EDGES   371712
#define S0 4278
#define S1 2081
#define S2 5257
#define F0 3066
#define F1 2081
#define F2 5257
#define NBLK 91   // ceil(11616/128)
#define FC_KS 4   // split-K factor for input FCs
#define WPR 363   // adj bitmask words per row: 11616 == 363*32 exactly

typedef __attribute__((ext_vector_type(8))) short bf16x8;
typedef __attribute__((ext_vector_type(4))) float f32x4;

#define GL2LDS(g, l) __builtin_amdgcn_global_load_lds(                         \
    (const __attribute__((address_space(1))) unsigned int*)(g),                \
    (__attribute__((address_space(3))) unsigned int*)(l), 16, 0, 0)

__device__ __forceinline__ int slot_of(int row, int kg)
{
    return row * 4 + (kg ^ ((row >> 1) & 3));
}

// ---------------- init ----------------
__global__ void k_init(double* __restrict__ accum, int* __restrict__ indeg,
                       int* __restrict__ cursor)
{
    int i = blockIdx.x * blockDim.x + threadIdx.x;
    if (i < 2) accum[i] = 0.0;
    if (i < N_NODES) { indeg[i] = 0; cursor[i] = 0; }
}

__global__ void k_padzero(short* __restrict__ xh, short* __restrict__ xl)
{
    int i = blockIdx.x * blockDim.x + threadIdx.x;
    const int base  = N_NODES * NHID;
    const int total = (NROWPAD - N_NODES) * NHID;
    if (i < total) { xh[base + i] = 0; xl[base + i] = 0; }
}

// ---------------- adj -> bitmask (16.9 MB) ----------------
__global__ void k_adjbits(const float* __restrict__ adj, unsigned* __restrict__ bits)
{
    const long i = (long)blockIdx.x * 256 + threadIdx.x;   // word index
    const long total = (long)N_NODES * WPR;
    if (i >= total) return;
    const int r = (int)(i / WPR);
    const int w = (int)(i % WPR);
    const float4* rp = reinterpret_cast<const float4*>(adj + (long)r * N_NODES + w * 32);
    unsigned m = 0;
    #pragma unroll
    for (int j4 = 0; j4 < 8; ++j4) {
        float4 v = rp[j4];
        int b = j4 * 4;
        m |= (v.x != 0.f) ? (1u << b)       : 0u;
        m |= (v.y != 0.f) ? (1u << (b + 1)) : 0u;
        m |= (v.z != 0.f) ? (1u << (b + 2)) : 0u;
        m |= (v.w != 0.f) ? (1u << (b + 3)) : 0u;
    }
    bits[i] = m;
}

// ---------------- CSR build ----------------
__global__ void k_count(const int* __restrict__ dst, int* __restrict__ indeg)
{
    int e = blockIdx.x * blockDim.x + threadIdx.x;
    if (e < EDGES) atomicAdd(&indeg[dst[e]], 1);
}

__global__ void k_scan(const int* __restrict__ indeg, int* __restrict__ rowptr)
{
    __shared__ int part[256];
    const int t = threadIdx.x;
    const int chunk = (N_NODES + 255) / 256;
    const int base = t * chunk;
    int s = 0;
    for (int i = 0; i < chunk; ++i) {
        int idx = base + i;
        if (idx < N_NODES) s += indeg[idx];
    }
    part[t] = s;
    __syncthreads();
    if (t == 0) for (int i = 1; i < 256; ++i) part[i] += part[i - 1];
    __syncthreads();
    int run = (t == 0) ? 0 : part[t - 1];
    for (int i = 0; i < chunk; ++i) {
        int idx = base + i;
        if (idx < N_NODES) { rowptr[idx] = run; run += indeg[idx]; }
    }
    if (t == 0) rowptr[N_NODES] = part[255];
}

__global__ void k_fill(const int* __restrict__ src, const int* __restrict__ dst,
                       const float* __restrict__ ew, const int* __restrict__ rowptr,
                       int* __restrict__ cursor, int* __restrict__ csrc,
                       float* __restrict__ cw)
{
    int e = blockIdx.x * blockDim.x + threadIdx.x;
    if (e >= EDGES) return;
    int d = dst[e];
    int pos = rowptr[d] + atomicAdd(&cursor[d], 1);
    csrc[pos] = src[e];
    cw[pos]   = ew[e];
}

// ---------------- bf16 hi/lo split ----------------
__device__ __forceinline__ void split_bf16(float f, short& hi, short& lo)
{
    unsigned u  = __float_as_uint(f);
    unsigned hr = (u + 0x7FFFu + ((u >> 16) & 1u)) & 0xFFFF0000u;
    float    fh = __uint_as_float(hr);
    float    fl = f - fh;
    unsigned ul = __float_as_uint(fl);
    unsigned lr = ul + 0x7FFFu + ((ul >> 16) & 1u);
    hi = (short)(hr >> 16);
    lo = (short)(lr >> 16);
}

// elementwise split with row+col zero-padding: in[R][C] fp32 -> oh/ol[Rpad][Cpad]
__global__ void k_splitpad(const float* __restrict__ in, short* __restrict__ oh,
                           short* __restrict__ ol, int R, int C, int Cpad)
{
    const int c = blockIdx.x * 256 + threadIdx.x;
    const int r = blockIdx.y;
    if (c >= Cpad) return;
    float f = (r < R && c < C) ? in[(long)r * C + c] : 0.f;
    short h, l;
    split_bf16(f, h, l);
    oh[(long)r * Cpad + c] = h;
    ol[(long)r * Cpad + c] = l;
}

// transpose + split: in[R][C] fp32 -> oh/ol[Cpad][Rpad] bf16 (zero pads both dims)
__global__ void k_tsplit(const float* __restrict__ in, short* __restrict__ oh,
                         short* __restrict__ ol, int R, int C, int Rpad, int Cpad)
{
    __shared__ float tile[32][33];
    const int cb = blockIdx.x * 32, rb = blockIdx.y * 32;
    const int tx = threadIdx.x, ty = threadIdx.y;   // 32 x 8
    #pragma unroll
    for (int i = ty; i < 32; i += 8) {
        int r = rb + i, c = cb + tx;
        tile[i][tx] = (r < R && c < C) ? in[(long)r * C + c] : 0.f;
    }
    __syncthreads();
    #pragma unroll
    for (int i = ty; i < 32; i += 8) {
        int row = cb + i, col = rb + tx;
        if (row < Cpad && col < Rpad) {
            short h, l;
            split_bf16(tile[tx][i], h, l);
            oh[(long)row * Rpad + col] = h;
            ol[(long)row * Rpad + col] = l;
        }
    }
}

// stage one 128x32 bf16 panel via global_load_lds (pre-swizzled source, linear dest)
__device__ __forceinline__ void stage_gl(const short* __restrict__ src, int ldk,
                                         int k0, short* ldsPanel, int lane)
{
    #pragma unroll
    for (int i = 0; i < 8; ++i) {
        int ci  = i * 64 + lane;
        int row = ci >> 2;
        int kgs = (ci & 3) ^ ((row >> 1) & 3);
        const short* g = src + (long)row * ldk + k0 + kgs * 8;
        GL2LDS(g, (char*)ldsPanel + i * 1024);
    }
}

// ---------------- GEMM: both operands pre-split bf16, gload_lds staged ----------------
__global__ __launch_bounds__(256, 3)
void k_gemm_bb(const short* __restrict__ Agh, const short* __restrict__ Agl,
               const short* __restrict__ Bgh, const short* __restrict__ Bgl,
               const float* __restrict__ bias, float* __restrict__ C,
               int M, int NN, int Kpad, int ldk)
{
    __shared__ short P[4][4096];
    const int t = threadIdx.x, lane = t & 63, w = t >> 6;
    const int rowBase = blockIdx.y * 128, colBase = blockIdx.x * 128;
    const int wm = (w >> 1) * 64, wn = (w & 1) * 64;
    const int kg = lane >> 4, fr = lane & 15;

    const short* srcs[4] = { Agh + (long)rowBase * ldk, Agl + (long)rowBase * ldk,
                             Bgh + (long)colBase * ldk, Bgl + (long)colBase * ldk };
    const short* mySrc = srcs[w];

    int offA[4], offB[4];
    #pragma unroll
    for (int f = 0; f < 4; ++f) {
        int rA = wm + f * 16 + fr, rB = wn + f * 16 + fr;
        offA[f] = slot_of(rA, kg) * 8;
        offB[f] = slot_of(rB, kg) * 8;
    }

    f32x4 acc[4][4];
    #pragma unroll
    for (int i = 0; i < 4; ++i)
        #pragma unroll
        for (int j = 0; j < 4; ++j)
            acc[i][j] = (f32x4){0.f, 0.f, 0.f, 0.f};

    for (int k0 = 0; k0 < Kpad; k0 += 32) {
        stage_gl(mySrc, ldk, k0, &P[w][0], lane);
        __syncthreads();
        bf16x8 ah[4], al[4], bh[4], bl[4];
        #pragma unroll
        for (int f = 0; f < 4; ++f) {
            ah[f] = *(const bf16x8*)&P[0][offA[f]];
            al[f] = *(const bf16x8*)&P[1][offA[f]];
            bh[f] = *(const bf16x8*)&P[2][offB[f]];
            bl[f] = *(const bf16x8*)&P[3][offB[f]];
        }
        #pragma unroll
        for (int i = 0; i < 4; ++i)
            #pragma unroll
            for (int j = 0; j < 4; ++j) {
                acc[i][j] = __builtin_amdgcn_mfma_f32_16x16x32_bf16(ah[i], bh[j], acc[i][j], 0, 0, 0);
                acc[i][j] = __builtin_amdgcn_mfma_f32_16x16x32_bf16(ah[i], bl[j], acc[i][j], 0, 0, 0);
                acc[i][j] = __builtin_amdgcn_mfma_f32_16x16x32_bf16(al[i], bh[j], acc[i][j], 0, 0, 0);
            }
        __syncthreads();
    }

    #pragma unroll
    for (int i = 0; i < 4; ++i) {
        #pragma unroll
        for (int q = 0; q < 4; ++q) {
            int r = rowBase + wm + i * 16 + kg * 4 + q;
            if (r >= M) continue;
            #pragma unroll
            for (int j = 0; j < 4; ++j) {
                int c = colBase + wn + j * 16 + fr;
                if (c < NN)
                    C[(long)r * NN + c] = acc[i][j][q] + (bias ? bias[c] : 0.f);
            }
        }
    }
}

// ---------------- split-K partial GEMM (for FCs): z-th K chunk -> fp32 partial ----------------
__global__ __launch_bounds__(256, 3)
void k_gemm_red(const short* __restrict__ Agh, const short* __restrict__ Agl,
                const short* __restrict__ Bgh, const short* __restrict__ Bgl,
                float* __restrict__ Cpart, int M, int ldk, int kChunk)
{
    __shared__ short P[4][4096];
    const int t = threadIdx.x, lane = t & 63, w = t >> 6;
    const int rowBase = blockIdx.y * 128, colBase = blockIdx.x * 128;
    const int z = blockIdx.z;
    const int wm = (w >> 1) * 64, wn = (w & 1) * 64;
    const int kg = lane >> 4, fr = lane & 15;

    const short* srcs[4] = { Agh + (long)rowBase * ldk, Agl + (long)rowBase * ldk,
                             Bgh + (long)colBase * ldk, Bgl + (long)colBase * ldk };
    const short* mySrc = srcs[w];

    int offA[4], offB[4];
    #pragma unroll
    for (int f = 0; f < 4; ++f) {
        int rA = wm + f * 16 + fr, rB = wn + f * 16 + fr;
        offA[f] = slot_of(rA, kg) * 8;
        offB[f] = slot_of(rB, kg) * 8;
    }

    f32x4 acc[4][4];
    #pragma unroll
    for (int i = 0; i < 4; ++i)
        #pragma unroll
        for (int j = 0; j < 4; ++j)
            acc[i][j] = (f32x4){0.f, 0.f, 0.f, 0.f};

    const int kEnd = z * kChunk + kChunk;
    for (int k0 = z * kChunk; k0 < kEnd; k0 += 32) {
        stage_gl(mySrc, ldk, k0, &P[w][0], lane);
        __syncthreads();
        bf16x8 ah[4], al[4], bh[4], bl[4];
        #pragma unroll
        for (int f = 0; f < 4; ++f) {
            ah[f] = *(const bf16x8*)&P[0][offA[f]];
            al[f] = *(const bf16x8*)&P[1][offA[f]];
            bh[f] = *(const bf16x8*)&P[2][offB[f]];
            bl[f] = *(const bf16x8*)&P[3][offB[f]];
        }
        #pragma unroll
        for (int i = 0; i < 4; ++i)
            #pragma unroll
            for (int j = 0; j < 4; ++j) {
                acc[i][j] = __builtin_amdgcn_mfma_f32_16x16x32_bf16(ah[i], bh[j], acc[i][j], 0, 0, 0);
                acc[i][j] = __builtin_amdgcn_mfma_f32_16x16x32_bf16(ah[i], bl[j], acc[i][j], 0, 0, 0);
                acc[i][j] = __builtin_amdgcn_mfma_f32_16x16x32_bf16(al[i], bh[j], acc[i][j], 0, 0, 0);
            }
        __syncthreads();
    }

    #pragma unroll
    for (int i = 0; i < 4; ++i) {
        #pragma unroll
        for (int q = 0; q < 4; ++q) {
            int r = rowBase + wm + i * 16 + kg * 4 + q;
            if (r >= M) continue;
            #pragma unroll
            for (int j = 0; j < 4; ++j) {
                int c = colBase + wn + j * 16 + fr;
                Cpart[((long)z * M + r) * NHID + c] = acc[i][j][q];
            }
        }
    }
}

// ---------------- FC reduce: sum FC_KS partials + bias, write fp32 + split ----------------
__global__ void k_fcreduce(const float* __restrict__ Cpart, const float* __restrict__ bias,
                           int M, float* __restrict__ xo, short* __restrict__ oh,
                           short* __restrict__ ol)
{
    const int r = blockIdx.x;
    const int c = threadIdx.x << 2;   // 128 threads
    float4 s = *reinterpret_cast<const float4*>(bias + c);
    #pragma unroll
    for (int z = 0; z < FC_KS; ++z) {
        const float4 p = *reinterpret_cast<const float4*>(Cpart + ((long)z * M + r) * NHID + c);
        s.x += p.x; s.y += p.y; s.z += p.z; s.w += p.w;
    }
    *reinterpret_cast<float4*>(xo + (long)r * NHID + c) = s;
    short4 h, l;
    split_bf16(s.x, h.x, l.x); split_bf16(s.y, h.y, l.y);
    split_bf16(s.z, h.z, l.z); split_bf16(s.w, h.w, l.w);
    *reinterpret_cast<short4*>(oh + (long)r * NHID + c) = h;
    *reinterpret_cast<short4*>(ol + (long)r * NHID + c) = l;
}

// ---------------- zloss: upper-triangle blocks of z = x x^T, bitmask adj ----------------
__global__ __launch_bounds__(256, 3)
void k_zloss(const short* __restrict__ xh, const short* __restrict__ xl,
             const unsigned* __restrict__ bits, double* __restrict__ accum)
{
    __shared__ short P[4][4096];
    __shared__ float ztr[4][16][17];
    __shared__ float red[256];
    const int t = threadIdx.x, lane = t & 63, w = t >> 6;

    int b = blockIdx.x, R = 0;
    while (b >= NBLK - R) { b -= NBLK - R; ++R; }
    const int Cb = R + b;
    const int rowBase = R * 128, colBase = Cb * 128;
    const int diag = (Cb == R);

    const int wm = (w >> 1) * 64, wn = (w & 1) * 64;
    const int kg = lane >> 4, fr = lane & 15;

    const short* srcs[4] = { xh + (long)rowBase * NHID, xl + (long)rowBase * NHID,
                             xh + (long)colBase * NHID, xl + (long)colBase * NHID };
    const short* mySrc = srcs[w];

    int offA[4], offB[4];
    #pragma unroll
    for (int f = 0; f < 4; ++f) {
        int rA = wm + f * 16 + fr, rB = wn + f * 16 + fr;
        offA[f] = slot_of(rA, kg) * 8;
        offB[f] = slot_of(rB, kg) * 8;
    }

    f32x4 acc[4][4];
    #pragma unroll
    for (int i = 0; i < 4; ++i)
        #pragma unroll
        for (int j = 0; j < 4; ++j)
            acc[i][j] = (f32x4){0.f, 0.f, 0.f, 0.f};

    for (int k0 = 0; k0 < NHID; k0 += 32) {
        stage_gl(mySrc, NHID, k0, &P[w][0], lane);
        __syncthreads();
        bf16x8 ah[4], al[4], bh[4], bl[4];
        #pragma unroll
        for (int f = 0; f < 4; ++f) {
            ah[f] = *(const bf16x8*)&P[0][offA[f]];
            al[f] = *(const bf16x8*)&P[1][offA[f]];
            bh[f] = *(const bf16x8*)&P[2][offB[f]];
            bl[f] = *(const bf16x8*)&P[3][offB[f]];
        }
        #pragma unroll
        for (int i = 0; i < 4; ++i)
            #pragma unroll
            for (int j = 0; j < 4; ++j) {
                acc[i][j] = __builtin_amdgcn_mfma_f32_16x16x32_bf16(ah[i], bh[j], acc[i][j], 0, 0, 0);
                acc[i][j] = __builtin_amdgcn_mfma_f32_16x16x32_bf16(ah[i], bl[j], acc[i][j], 0, 0, 0);
                acc[i][j] = __builtin_amdgcn_mfma_f32_16x16x32_bf16(al[i], bh[j], acc[i][j], 0, 0, 0);
            }
        __syncthreads();
    }

    float local = 0.f;
    // pass 1: softplus + direct adj[r][c] (bitmask word per lane, L1/L2-hot)
    #pragma unroll
    for (int i = 0; i < 4; ++i) {
        #pragma unroll
        for (int q = 0; q < 4; ++q) {
            int r = rowBase + wm + i * 16 + kg * 4 + q;
            if (r >= N_NODES) continue;
            #pragma unroll
            for (int j = 0; j < 4; ++j) {
                int c = colBase + wn + j * 16 + fr;
                if (c >= N_NODES) continue;
                float z  = acc[i][j][q];
                float sp = fmaxf(z, 0.f) + __logf(1.f + __expf(-fabsf(z)));
                unsigned wd = bits[(long)r * WPR + (c >> 5)];
                float az = ((wd >> (c & 31)) & 1u) ? z : 0.f;
                local += diag ? (sp - az) : (2.f * sp - az);
            }
        }
    }
    // pass 2 (off-diag): adj[c][r] via per-wave fragment transpose
    if (!diag) {
        #pragma unroll
        for (int i = 0; i < 4; ++i) {
            #pragma unroll
            for (int j = 0; j < 4; ++j) {
                #pragma unroll
                for (int q = 0; q < 4; ++q)
                    ztr[w][kg * 4 + q][fr] = acc[i][j][q];
                #pragma unroll
                for (int q = 0; q < 4; ++q) {
                    float zt = ztr[w][fr][kg * 4 + q];
                    int cc = colBase + wn + j * 16 + kg * 4 + q;   // bit row
                    int rr = rowBase + wm + i * 16 + fr;           // bit col
                    if (cc < N_NODES && rr < N_NODES) {
                        unsigned wd = bits[(long)cc * WPR + (rr >> 5)];
                        if ((wd >> (rr & 31)) & 1u) local -= zt;
                    }
                }
            }
        }
    }
    red[t] = local;
    __syncthreads();
    for (int sft = 128; sft > 0; sft >>= 1) {
        if (t < sft) red[t] += red[t + sft];
        __syncthreads();
    }
    if (t == 0) atomicAdd(accum, (double)red[0]);
}

// ---------------- SpMM single pass (512 ch via 2x float4) + fused split ----------------
__global__ void k_spmm(const float* __restrict__ y, const float* __restrict__ xold,
                       const int* __restrict__ rowptr, const int* __restrict__ csrc,
                       const float* __restrict__ cw, const float* __restrict__ bias,
                       int do_relu, float* __restrict__ xnew,
                       short* __restrict__ xh, short* __restrict__ xl)
{
    const int wv   = threadIdx.x >> 6;
    const int lane = threadIdx.x & 63;
    const int n    = blockIdx.x * 4 + wv;       // 2904*4 == 11616 exactly
    const int c1   = lane << 2;
    const int c2   = c1 + 256;
    float4 s1 = make_float4(0.f, 0.f, 0.f, 0.f);
    float4 s2 = make_float4(0.f, 0.f, 0.f, 0.f);
    const int beg = rowptr[n], end = rowptr[n + 1];
    for (int e = beg; e < end; ++e) {
        int   sn = csrc[e];
        float wt = cw[e];
        const float* yr = y + (long)sn * NHID;
        const float4 y1 = *reinterpret_cast<const float4*>(yr + c1);
        const float4 y2 = *reinterpret_cast<const float4*>(yr + c2);
        s1.x = fmaf(wt, y1.x, s1.x); s1.y = fmaf(wt, y1.y, s1.y);
        s1.z = fmaf(wt, y1.z, s1.z); s1.w = fmaf(wt, y1.w, s1.w);
        s2.x = fmaf(wt, y2.x, s2.x); s2.y = fmaf(wt, y2.y, s2.y);
        s2.z = fmaf(wt, y2.z, s2.z); s2.w = fmaf(wt, y2.w, s2.w);
    }
    const float4 b1 = *reinterpret_cast<const float4*>(bias + c1);
    const float4 b2 = *reinterpret_cast<const float4*>(bias + c2);
    float4 o1, o2;
    o1.x = s1.x + b1.x; o1.y = s1.y + b1.y; o1.z = s1.z + b1.z; o1.w = s1.w + b1.w;
    o2.x = s2.x + b2.x; o2.y = s2.y + b2.y; o2.z = s2.z + b2.z; o2.w = s2.w + b2.w;
    if (do_relu) {
        o1.x = fmaxf(o1.x, 0.f); o1.y = fmaxf(o1.y, 0.f);
        o1.z = fmaxf(o1.z, 0.f); o1.w = fmaxf(o1.w, 0.f);
        o2.x = fmaxf(o2.x, 0.f); o2.y = fmaxf(o2.y, 0.f);
        o2.z = fmaxf(o2.z, 0.f); o2.w = fmaxf(o2.w, 0.f);
    } else {
        const float4 x1 = *reinterpret_cast<const float4*>(xold + (long)n * NHID + c1);
        const float4 x2 = *reinterpret_cast<const float4*>(xold + (long)n * NHID + c2);
        o1.x += x1.x; o1.y += x1.y; o1.z += x1.z; o1.w += x1.w;
        o2.x += x2.x; o2.y += x2.y; o2.z += x2.z; o2.w += x2.w;
    }
    *reinterpret_cast<float4*>(xnew + (long)n * NHID + c1) = o1;
    *reinterpret_cast<float4*>(xnew + (long)n * NHID + c2) = o2;
    short4 h, l;
    split_bf16(o1.x, h.x, l.x); split_bf16(o1.y, h.y, l.y);
    split_bf16(o1.z, h.z, l.z); split_bf16(o1.w, h.w, l.w);
    *reinterpret_cast<short4*>(xh + (long)n * NHID + c1) = h;
    *reinterpret_cast<short4*>(xl + (long)n * NHID + c1) = l;
    split_bf16(o2.x, h.x, l.x); split_bf16(o2.y, h.y, l.y);
    split_bf16(o2.z, h.z, l.z); split_bf16(o2.w, h.w, l.w);
    *reinterpret_cast<short4*>(xh + (long)n * NHID + c2) = h;
    *reinterpret_cast<short4*>(xl + (long)n * NHID + c2) = l;
}

// ---------------- recon loss ----------------
__global__ void k_recon(const float* __restrict__ r0, const float* __restrict__ X0,
                        double* __restrict__ accum)
{
    const int row = blockIdx.x;
    const int t = threadIdx.x;   // 256
    float dot = 0.f, nr = 0.f, nf = 0.f;
    for (int c = t; c < F0; c += 256) {
        float a = r0[(long)row * F0 + c];
        float b = X0[(long)row * F0 + c];
        dot = fmaf(a, b, dot);
        nr  = fmaf(a, a, nr);
        nf  = fmaf(b, b, nf);
    }
    #pragma unroll
    for (int o = 32; o > 0; o >>= 1) {
        dot += __shfl_down(dot, o);
        nr  += __shfl_down(nr, o);
        nf  += __shfl_down(nf, o);
    }
    __shared__ float sd[3][4];
    const int lane = t & 63, wid = t >> 6;
    if (lane == 0) { sd[0][wid] = dot; sd[1][wid] = nr; sd[2][wid] = nf; }
    __syncthreads();
    if (t == 0) {
        float d = sd[0][0] + sd[0][1] + sd[0][2] + sd[0][3];
        float a = sd[1][0] + sd[1][1] + sd[1][2] + sd[1][3];
        float b = sd[2][0] + sd[2][1] + sd[2][2] + sd[2][3];
        float cosv = d / (fmaxf(sqrtf(a), 1e-12f) * fmaxf(sqrtf(b), 1e-12f));
        float v = 1.f - cosv;
        atomicAdd(accum + 1, (double)(v * v * v));
    }
}

__global__ void k_final(const double* __restrict__ accum, float* __restrict__ out)
{
    if (threadIdx.x == 0) {
        out[45082958] = (float)(accum[0] / ((double)N_NODES * (double)N_NODES));
        out[45082959] = (float)(accum[1] / (double)S0);
    }
}

extern "C" void kernel_launch(void* const* d_in, const int* in_sizes, int n_in,
                              void* d_out, int out_size, void* d_ws, size_t ws_size,
                              hipStream_t stream)
{
    const float* X0  = (const float*)d_in[0];
    const float* X1  = (const float*)d_in[1];
    const float* X2  = (const float*)d_in[2];
    const int*   src = (const int*)d_in[3];
    const int*   dst = (const int*)d_in[4];
    const float* ew  = (const float*)d_in[5];
    const float* adj = (const float*)d_in[6];
    const float* fcW[3]  = {(const float*)d_in[7],  (const float*)d_in[9],  (const float*)d_in[11]};
    const float* fcB[3]  = {(const float*)d_in[8],  (const float*)d_in[10], (const float*)d_in[12]};
    const float* encW = (const float*)d_in[13];
    const float* encB = (const float*)d_in[14];
    const float* decW = (const float*)d_in[15];
    const float* decB = (const float*)d_in[16];
    const float* outW[3] = {(const float*)d_in[17], (const float*)d_in[19], (const float*)d_in[21]};
    const float* outB[3] = {(const float*)d_in[18], (const float*)d_in[20], (const float*)d_in[22]};
    float* out = (float*)d_out;

    const int FD[3]     = {F0, F1, F2};
    const int FPAD[3]   = {(F0 + 127) & ~127, (F1 + 127) & ~127, (F2 + 127) & ~127}; // K pad (128-mult)
    const int SPAD[3]   = {(S0 + 127) & ~127, (S1 + 127) & ~127, (S2 + 127) & ~127}; // row pad
    const int SD[3]     = {S0, S1, S2};
    const float* XD[3]  = {X0, X1, X2};

    char* ws = (char*)d_ws;
    size_t off = 0;
    auto alloc = [&](size_t bytes) { void* p = ws + off; off += (bytes + 255) & ~(size_t)255; return p; };

    double* accum = (double*)alloc(16);
    const size_t XB = (size_t)N_NODES * NHID * sizeof(float);
    float* xbuf = (float*)alloc(XB);
    float* ybuf = (float*)alloc(XB);   // FC phase: aliased as split-K partial buffer
    float* xalt = (float*)alloc(XB);   // (cpart spans ybuf+xalt, 47.6MB >= 43.1MB needed)
    short* xh   = (short*)alloc((size_t)NROWPAD * NHID * 2);
    short* xl   = (short*)alloc((size_t)NROWPAD * NHID * 2);
    // X split staging (max over the 3 types); reused later for outW splits
    const size_t XSmax = (size_t)5376 * 5376;
    short* Xsh  = (short*)alloc(XSmax * 2);
    short* Xsl  = (short*)alloc(XSmax * 2);
    // fc weight split (max 512*5376)
    short* fcWh = (short*)alloc((size_t)NHID * 5376 * 2);
    short* fcWl = (short*)alloc((size_t)NHID * 5376 * 2);
    short* wTh  = (short*)alloc((size_t)8 * NHID * NHID * 2);
    short* wTl  = (short*)alloc((size_t)8 * NHID * NHID * 2);
    unsigned* bits = (unsigned*)alloc((size_t)N_NODES * WPR * 4);   // 16.9 MB
    int* indeg  = (int*)alloc((size_t)N_NODES * 4);
    int* rowptr = (int*)alloc((size_t)(N_NODES + 1) * 4);
    int* cursor = (int*)alloc((size_t)N_NODES * 4);
    int* csrc   = (int*)alloc((size_t)EDGES * 4);
    float* cw   = (float*)alloc((size_t)EDGES * 4);

    float* cpart = ybuf;   // alias: free until first layer GEMM

    // ---- CSR build + pad zero + adj bitmask ----
    k_init<<<dim3((N_NODES + 255) / 256), dim3(256), 0, stream>>>(accum, indeg, cursor);
    k_padzero<<<dim3(((NROWPAD - N_NODES) * NHID + 255) / 256), dim3(256), 0, stream>>>(xh, xl);
    k_count<<<dim3((EDGES + 255) / 256), dim3(256), 0, stream>>>(dst, indeg);
    k_scan<<<dim3(1), dim3(256), 0, stream>>>(indeg, rowptr);
    k_fill<<<dim3((EDGES + 255) / 256), dim3(256), 0, stream>>>(src, dst, ew, rowptr, cursor, csrc, cw);
    {
        long words = (long)N_NODES * WPR;
        k_adjbits<<<dim3((unsigned)((words + 255) / 256)), dim3(256), 0, stream>>>(adj, bits);
    }

    auto tgrid = [](int Cpad, int Rpad) { return dim3((unsigned)((Cpad + 31) / 32), (unsigned)((Rpad + 31) / 32)); };
    auto ggrid = [](int m, int nn) { return dim3((unsigned)((nn + 127) / 128), (unsigned)((m + 127) / 128)); };

    // ---- enc/dec weight transpose+split ----
    for (int i = 0; i < 4; ++i) {
        k_tsplit<<<tgrid(NHID, NHID), dim3(32, 8), 0, stream>>>(
            encW + (size_t)i * NHID * NHID, wTh + (size_t)i * NHID * NHID,
            wTl + (size_t)i * NHID * NHID, NHID, NHID, NHID, NHID);
        k_tsplit<<<tgrid(NHID, NHID), dim3(32, 8), 0, stream>>>(
            decW + (size_t)i * NHID * NHID, wTh + (size_t)(4 + i) * NHID * NHID,
            wTl + (size_t)(4 + i) * NHID * NHID, NHID, NHID, NHID, NHID);
    }

    // ---- input FCs via split-K ----
    {
        size_t rowoff = 0;
        for (int i = 0; i < 3; ++i) {
            k_splitpad<<<dim3((FPAD[i] + 255) / 256, SPAD[i]), dim3(256), 0, stream>>>(
                XD[i], Xsh, Xsl, SD[i], FD[i], FPAD[i]);
            k_tsplit<<<tgrid(NHID, FPAD[i]), dim3(32, 8), 0, stream>>>(
                fcW[i], fcWh, fcWl, FD[i], NHID, FPAD[i], NHID);
            k_gemm_red<<<dim3(NHID / 128, SPAD[i] / 128, FC_KS), dim3(256), 0, stream>>>(
                Xsh, Xsl, fcWh, fcWl, cpart, SD[i], FPAD[i], FPAD[i] / FC_KS);
            k_fcreduce<<<dim3(SD[i]), dim3(128), 0, stream>>>(
                cpart, fcB[i], SD[i], xbuf + rowoff * NHID,
                xh + rowoff * NHID, xl + rowoff * NHID);
            rowoff += SD[i];
        }
    }

    // ---- 8 GNN layers (split fused into spmm) ----
    float* x  = xbuf;
    float* xn = xalt;
    for (int phase = 0; phase < 2; ++phase) {
        const float* B = phase ? decB : encB;
        for (int i = 0; i < 4; ++i) {
            k_gemm_bb<<<ggrid(N_NODES, NHID), dim3(256), 0, stream>>>(
                xh, xl, wTh + (size_t)(phase * 4 + i) * NHID * NHID,
                wTl + (size_t)(phase * 4 + i) * NHID * NHID,
                nullptr, ybuf, N_NODES, NHID, NHID, NHID);
            k_spmm<<<dim3(N_NODES / 4), dim3(256), 0, stream>>>(
                ybuf, x, rowptr, csrc, cw, B + (size_t)i * NHID, (i == 0) ? 1 : 0,
                xn, xh, xl);
            float* tmp = x; x = xn; xn = tmp;
        }
    }

    // ---- outW transpose+split (into the now-free X staging region) ----
    short* oWh = Xsh;
    short* oWl = Xsl;
    {
        short *ph = oWh, *pl = oWl;
        for (int i = 0; i < 3; ++i) {
            int FDP = (FD[i] + 127) & ~127;
            k_tsplit<<<tgrid(FDP, NHID), dim3(32, 8), 0, stream>>>(
                outW[i], ph, pl, NHID, FD[i], NHID, FDP);
            ph += (size_t)FDP * NHID; pl += (size_t)FDP * NHID;
        }
    }

    // ---- output projections ----
    {
        short *ph = oWh, *pl = oWl;
        float* oo = out;
        size_t rowoff = 0;
        for (int i = 0; i < 3; ++i) {
            int FDP = (FD[i] + 127) & ~127;
            k_gemm_bb<<<ggrid(SD[i], FD[i]), dim3(256), 0, stream>>>(
                xh + rowoff * NHID, xl + rowoff * NHID, ph, pl, outB[i], oo,
                SD[i], FD[i], NHID, NHID);
            ph += (size_t)FDP * NHID; pl += (size_t)FDP * NHID;
            oo += (size_t)SD[i] * FD[i];
            rowoff += SD[i];
        }
    }

    // ---- losses ----
    k_zloss<<<dim3(NBLK * (NBLK + 1) / 2), dim3(256), 0, stream>>>(xh, xl, bits, accum);
    k_recon<<<dim3(S0), dim3(256), 0, stream>>>(out, X0, accum);
    k_final<<<dim3(1), dim3(64), 0, stream>>>(accum, out);
}

// Round 10
// 2252.619 us; speedup vs baseline: 1.5005x; 1.0172x over previous
//
#include <hip/hip_runtime.h>
#include <math.h>

#define N_NODES 11616
#define NROWPAD 11776   // 92*128, padded rows for xh/xl
#define NHID    512
#define EDGES   371712
#define S0 4278
#define S1 2081
#define S2 5257
#define F0 3066
#define F1 2081
#define F2 5257
#define NBLK 91    // ceil(11616/128)
#define NZBLK 4186 // NBLK*(NBLK+1)/2
#define FC_KS 4    // split-K factor for input FCs
#define WPR 363    // adj bitmask words per row: 11616 == 363*32 exactly

typedef __attribute__((ext_vector_type(8))) short bf16x8;
typedef __attribute__((ext_vector_type(4))) float f32x4;

#define GL2LDS(g, l) __builtin_amdgcn_global_load_lds(                         \
    (const __attribute__((address_space(1))) unsigned int*)(g),                \
    (__attribute__((address_space(3))) unsigned int*)(l), 16, 0, 0)

__device__ __forceinline__ int slot_of(int row, int kg)
{
    return row * 4 + (kg ^ ((row >> 1) & 3));
}

__device__ __forceinline__ float bf2f(short s)
{
    return __uint_as_float(((unsigned)(unsigned short)s) << 16);
}

// ---------------- init ----------------
__global__ void k_init(double* __restrict__ accum, int* __restrict__ indeg,
                       int* __restrict__ cursor)
{
    int i = blockIdx.x * blockDim.x + threadIdx.x;
    if (i < 2) accum[i] = 0.0;
    if (i < N_NODES) { indeg[i] = 0; cursor[i] = 0; }
}

__global__ void k_padzero(short* __restrict__ xh, short* __restrict__ xl)
{
    int i = blockIdx.x * blockDim.x + threadIdx.x;
    const int base  = N_NODES * NHID;
    const int total = (NROWPAD - N_NODES) * NHID;
    if (i < total) { xh[base + i] = 0; xl[base + i] = 0; }
}

// ---------------- adj -> bitmask (16.9 MB) ----------------
__global__ void k_adjbits(const float* __restrict__ adj, unsigned* __restrict__ bits)
{
    const long i = (long)blockIdx.x * 256 + threadIdx.x;   // word index
    const long total = (long)N_NODES * WPR;
    if (i >= total) return;
    const int r = (int)(i / WPR);
    const int w = (int)(i % WPR);
    const float4* rp = reinterpret_cast<const float4*>(adj + (long)r * N_NODES + w * 32);
    unsigned m = 0;
    #pragma unroll
    for (int j4 = 0; j4 < 8; ++j4) {
        float4 v = rp[j4];
        int b = j4 * 4;
        m |= (v.x != 0.f) ? (1u << b)       : 0u;
        m |= (v.y != 0.f) ? (1u << (b + 1)) : 0u;
        m |= (v.z != 0.f) ? (1u << (b + 2)) : 0u;
        m |= (v.w != 0.f) ? (1u << (b + 3)) : 0u;
    }
    bits[i] = m;
}

// ---------------- CSR build ----------------
__global__ void k_count(const int* __restrict__ dst, int* __restrict__ indeg)
{
    int e = blockIdx.x * blockDim.x + threadIdx.x;
    if (e < EDGES) atomicAdd(&indeg[dst[e]], 1);
}

__global__ void k_scan(const int* __restrict__ indeg, int* __restrict__ rowptr)
{
    __shared__ int part[256];
    const int t = threadIdx.x;
    const int chunk = (N_NODES + 255) / 256;
    const int base = t * chunk;
    int s = 0;
    for (int i = 0; i < chunk; ++i) {
        int idx = base + i;
        if (idx < N_NODES) s += indeg[idx];
    }
    part[t] = s;
    __syncthreads();
    if (t == 0) for (int i = 1; i < 256; ++i) part[i] += part[i - 1];
    __syncthreads();
    int run = (t == 0) ? 0 : part[t - 1];
    for (int i = 0; i < chunk; ++i) {
        int idx = base + i;
        if (idx < N_NODES) { rowptr[idx] = run; run += indeg[idx]; }
    }
    if (t == 0) rowptr[N_NODES] = part[255];
}

__global__ void k_fill(const int* __restrict__ src, const int* __restrict__ dst,
                       const float* __restrict__ ew, const int* __restrict__ rowptr,
                       int* __restrict__ cursor, int* __restrict__ csrc,
                       float* __restrict__ cw)
{
    int e = blockIdx.x * blockDim.x + threadIdx.x;
    if (e >= EDGES) return;
    int d = dst[e];
    int pos = rowptr[d] + atomicAdd(&cursor[d], 1);
    csrc[pos] = src[e];
    cw[pos]   = ew[e];
}

// ---------------- bf16 hi/lo split ----------------
__device__ __forceinline__ void split_bf16(float f, short& hi, short& lo)
{
    unsigned u  = __float_as_uint(f);
    unsigned hr = (u + 0x7FFFu + ((u >> 16) & 1u)) & 0xFFFF0000u;
    float    fh = __uint_as_float(hr);
    float    fl = f - fh;
    unsigned ul = __float_as_uint(fl);
    unsigned lr = ul + 0x7FFFu + ((ul >> 16) & 1u);
    hi = (short)(hr >> 16);
    lo = (short)(lr >> 16);
}

// elementwise split with row+col zero-padding: in[R][C] fp32 -> oh/ol[Rpad][Cpad]
__global__ void k_splitpad(const float* __restrict__ in, short* __restrict__ oh,
                           short* __restrict__ ol, int R, int C, int Cpad)
{
    const int c = blockIdx.x * 256 + threadIdx.x;
    const int r = blockIdx.y;
    if (c >= Cpad) return;
    float f = (r < R && c < C) ? in[(long)r * C + c] : 0.f;
    short h, l;
    split_bf16(f, h, l);
    oh[(long)r * Cpad + c] = h;
    ol[(long)r * Cpad + c] = l;
}

// transpose + split: in[R][C] fp32 -> oh/ol[Cpad][Rpad] bf16 (zero pads both dims)
__global__ void k_tsplit(const float* __restrict__ in, short* __restrict__ oh,
                         short* __restrict__ ol, int R, int C, int Rpad, int Cpad)
{
    __shared__ float tile[32][33];
    const int cb = blockIdx.x * 32, rb = blockIdx.y * 32;
    const int tx = threadIdx.x, ty = threadIdx.y;   // 32 x 8
    #pragma unroll
    for (int i = ty; i < 32; i += 8) {
        int r = rb + i, c = cb + tx;
        tile[i][tx] = (r < R && c < C) ? in[(long)r * C + c] : 0.f;
    }
    __syncthreads();
    #pragma unroll
    for (int i = ty; i < 32; i += 8) {
        int row = cb + i, col = rb + tx;
        if (row < Cpad && col < Rpad) {
            short h, l;
            split_bf16(tile[tx][i], h, l);
            oh[(long)row * Rpad + col] = h;
            ol[(long)row * Rpad + col] = l;
        }
    }
}

// stage one 128x32 bf16 panel via global_load_lds (pre-swizzled source, linear dest)
__device__ __forceinline__ void stage_gl(const short* __restrict__ src, int ldk,
                                         int k0, short* ldsPanel, int lane)
{
    #pragma unroll
    for (int i = 0; i < 8; ++i) {
        int ci  = i * 64 + lane;
        int row = ci >> 2;
        int kgs = (ci & 3) ^ ((row >> 1) & 3);
        const short* g = src + (long)row * ldk + k0 + kgs * 8;
        GL2LDS(g, (char*)ldsPanel + i * 1024);
    }
}

// ---------------- GEMM: both operands pre-split bf16, gload_lds staged ----------------
__global__ __launch_bounds__(256, 3)
void k_gemm_bb(const short* __restrict__ Agh, const short* __restrict__ Agl,
               const short* __restrict__ Bgh, const short* __restrict__ Bgl,
               const float* __restrict__ bias, float* __restrict__ C,
               int M, int NN, int Kpad, int ldk)
{
    __shared__ short P[4][4096];
    const int t = threadIdx.x, lane = t & 63, w = t >> 6;
    const int rowBase = blockIdx.y * 128, colBase = blockIdx.x * 128;
    const int wm = (w >> 1) * 64, wn = (w & 1) * 64;
    const int kg = lane >> 4, fr = lane & 15;

    const short* srcs[4] = { Agh + (long)rowBase * ldk, Agl + (long)rowBase * ldk,
                             Bgh + (long)colBase * ldk, Bgl + (long)colBase * ldk };
    const short* mySrc = srcs[w];

    int offA[4], offB[4];
    #pragma unroll
    for (int f = 0; f < 4; ++f) {
        int rA = wm + f * 16 + fr, rB = wn + f * 16 + fr;
        offA[f] = slot_of(rA, kg) * 8;
        offB[f] = slot_of(rB, kg) * 8;
    }

    f32x4 acc[4][4];
    #pragma unroll
    for (int i = 0; i < 4; ++i)
        #pragma unroll
        for (int j = 0; j < 4; ++j)
            acc[i][j] = (f32x4){0.f, 0.f, 0.f, 0.f};

    for (int k0 = 0; k0 < Kpad; k0 += 32) {
        stage_gl(mySrc, ldk, k0, &P[w][0], lane);
        __syncthreads();
        bf16x8 ah[4], al[4], bh[4], bl[4];
        #pragma unroll
        for (int f = 0; f < 4; ++f) {
            ah[f] = *(const bf16x8*)&P[0][offA[f]];
            al[f] = *(const bf16x8*)&P[1][offA[f]];
            bh[f] = *(const bf16x8*)&P[2][offB[f]];
            bl[f] = *(const bf16x8*)&P[3][offB[f]];
        }
        #pragma unroll
        for (int i = 0; i < 4; ++i)
            #pragma unroll
            for (int j = 0; j < 4; ++j) {
                acc[i][j] = __builtin_amdgcn_mfma_f32_16x16x32_bf16(ah[i], bh[j], acc[i][j], 0, 0, 0);
                acc[i][j] = __builtin_amdgcn_mfma_f32_16x16x32_bf16(ah[i], bl[j], acc[i][j], 0, 0, 0);
                acc[i][j] = __builtin_amdgcn_mfma_f32_16x16x32_bf16(al[i], bh[j], acc[i][j], 0, 0, 0);
            }
        __syncthreads();
    }

    #pragma unroll
    for (int i = 0; i < 4; ++i) {
        #pragma unroll
        for (int q = 0; q < 4; ++q) {
            int r = rowBase + wm + i * 16 + kg * 4 + q;
            if (r >= M) continue;
            #pragma unroll
            for (int j = 0; j < 4; ++j) {
                int c = colBase + wn + j * 16 + fr;
                if (c < NN)
                    C[(long)r * NN + c] = acc[i][j][q] + (bias ? bias[c] : 0.f);
            }
        }
    }
}

// ---------------- split-K partial GEMM (for FCs): z-th K chunk -> fp32 partial ----------------
__global__ __launch_bounds__(256, 3)
void k_gemm_red(const short* __restrict__ Agh, const short* __restrict__ Agl,
                const short* __restrict__ Bgh, const short* __restrict__ Bgl,
                float* __restrict__ Cpart, int M, int ldk, int kChunk)
{
    __shared__ short P[4][4096];
    const int t = threadIdx.x, lane = t & 63, w = t >> 6;
    const int rowBase = blockIdx.y * 128, colBase = blockIdx.x * 128;
    const int z = blockIdx.z;
    const int wm = (w >> 1) * 64, wn = (w & 1) * 64;
    const int kg = lane >> 4, fr = lane & 15;

    const short* srcs[4] = { Agh + (long)rowBase * ldk, Agl + (long)rowBase * ldk,
                             Bgh + (long)colBase * ldk, Bgl + (long)colBase * ldk };
    const short* mySrc = srcs[w];

    int offA[4], offB[4];
    #pragma unroll
    for (int f = 0; f < 4; ++f) {
        int rA = wm + f * 16 + fr, rB = wn + f * 16 + fr;
        offA[f] = slot_of(rA, kg) * 8;
        offB[f] = slot_of(rB, kg) * 8;
    }

    f32x4 acc[4][4];
    #pragma unroll
    for (int i = 0; i < 4; ++i)
        #pragma unroll
        for (int j = 0; j < 4; ++j)
            acc[i][j] = (f32x4){0.f, 0.f, 0.f, 0.f};

    const int kEnd = z * kChunk + kChunk;
    for (int k0 = z * kChunk; k0 < kEnd; k0 += 32) {
        stage_gl(mySrc, ldk, k0, &P[w][0], lane);
        __syncthreads();
        bf16x8 ah[4], al[4], bh[4], bl[4];
        #pragma unroll
        for (int f = 0; f < 4; ++f) {
            ah[f] = *(const bf16x8*)&P[0][offA[f]];
            al[f] = *(const bf16x8*)&P[1][offA[f]];
            bh[f] = *(const bf16x8*)&P[2][offB[f]];
            bl[f] = *(const bf16x8*)&P[3][offB[f]];
        }
        #pragma unroll
        for (int i = 0; i < 4; ++i)
            #pragma unroll
            for (int j = 0; j < 4; ++j) {
                acc[i][j] = __builtin_amdgcn_mfma_f32_16x16x32_bf16(ah[i], bh[j], acc[i][j], 0, 0, 0);
                acc[i][j] = __builtin_amdgcn_mfma_f32_16x16x32_bf16(ah[i], bl[j], acc[i][j], 0, 0, 0);
                acc[i][j] = __builtin_amdgcn_mfma_f32_16x16x32_bf16(al[i], bh[j], acc[i][j], 0, 0, 0);
            }
        __syncthreads();
    }

    #pragma unroll
    for (int i = 0; i < 4; ++i) {
        #pragma unroll
        for (int q = 0; q < 4; ++q) {
            int r = rowBase + wm + i * 16 + kg * 4 + q;
            if (r >= M) continue;
            #pragma unroll
            for (int j = 0; j < 4; ++j) {
                int c = colBase + wn + j * 16 + fr;
                Cpart[((long)z * M + r) * NHID + c] = acc[i][j][q];
            }
        }
    }
}

// ---------------- FC reduce: sum FC_KS partials + bias, split-only output ----------------
__global__ void k_fcreduce(const float* __restrict__ Cpart, const float* __restrict__ bias,
                           int M, short* __restrict__ oh, short* __restrict__ ol)
{
    const int r = blockIdx.x;
    const int c = threadIdx.x << 2;   // 128 threads
    float4 s = *reinterpret_cast<const float4*>(bias + c);
    #pragma unroll
    for (int z = 0; z < FC_KS; ++z) {
        const float4 p = *reinterpret_cast<const float4*>(Cpart + ((long)z * M + r) * NHID + c);
        s.x += p.x; s.y += p.y; s.z += p.z; s.w += p.w;
    }
    short4 h, l;
    split_bf16(s.x, h.x, l.x); split_bf16(s.y, h.y, l.y);
    split_bf16(s.z, h.z, l.z); split_bf16(s.w, h.w, l.w);
    *reinterpret_cast<short4*>(oh + (long)r * NHID + c) = h;
    *reinterpret_cast<short4*>(ol + (long)r * NHID + c) = l;
}

// ---------------- zloss: supertiled upper-triangle + XCD-chunked swizzle ----------------
__global__ __launch_bounds__(256, 3)
void k_zloss(const short* __restrict__ xh, const short* __restrict__ xl,
             const unsigned* __restrict__ bits, double* __restrict__ accum)
{
    __shared__ short P[4][4096];
    __shared__ float ztr[4][16][17];
    __shared__ float red[256];
    const int t = threadIdx.x, lane = t & 63, w = t >> 6;

    // --- XCD-chunked bijective swizzle (q=523, r=2 for NZBLK=4186, 8 XCDs) ---
    int L;
    {
        const int q = NZBLK / 8, rr = NZBLK % 8;
        int d = blockIdx.x;
        int xcd = d & 7, pos = d >> 3;
        L = (xcd < rr) ? xcd * (q + 1) + pos : rr * (q + 1) + (xcd - rr) * q + pos;
    }
    // --- supertile (4x4 blocks) decomposition of the upper triangle ---
    int R, Cb;
    {
        int RS = 0;
        for (;;) {
            int nr  = min(4, NBLK - RS * 4);
            int tri = nr * (nr + 1) / 2;
            int rest = NBLK - (RS + 1) * 4;
            if (rest < 0) rest = 0;
            int band = tri + nr * rest;
            if (L < band) break;
            L -= band; ++RS;
        }
        int nr  = min(4, NBLK - RS * 4);
        int tri = nr * (nr + 1) / 2;
        if (L < tri) {
            int r = 0;
            while (L >= nr - r) { L -= nr - r; ++r; }
            R  = RS * 4 + r;
            Cb = RS * 4 + r + L;
        } else {
            L -= tri;
            int CS = RS + 1;
            for (;;) {
                int nc  = min(4, NBLK - CS * 4);
                int cnt = nr * nc;
                if (L < cnt) { R = RS * 4 + L / nc; Cb = CS * 4 + L % nc; break; }
                L -= cnt; ++CS;
            }
        }
    }
    const int rowBase = R * 128, colBase = Cb * 128;
    const int diag = (Cb == R);

    const int wm = (w >> 1) * 64, wn = (w & 1) * 64;
    const int kg = lane >> 4, fr = lane & 15;

    const short* srcs[4] = { xh + (long)rowBase * NHID, xl + (long)rowBase * NHID,
                             xh + (long)colBase * NHID, xl + (long)colBase * NHID };
    const short* mySrc = srcs[w];

    int offA[4], offB[4];
    #pragma unroll
    for (int f = 0; f < 4; ++f) {
        int rA = wm + f * 16 + fr, rB = wn + f * 16 + fr;
        offA[f] = slot_of(rA, kg) * 8;
        offB[f] = slot_of(rB, kg) * 8;
    }

    f32x4 acc[4][4];
    #pragma unroll
    for (int i = 0; i < 4; ++i)
        #pragma unroll
        for (int j = 0; j < 4; ++j)
            acc[i][j] = (f32x4){0.f, 0.f, 0.f, 0.f};

    for (int k0 = 0; k0 < NHID; k0 += 32) {
        stage_gl(mySrc, NHID, k0, &P[w][0], lane);
        __syncthreads();
        bf16x8 ah[4], al[4], bh[4], bl[4];
        #pragma unroll
        for (int f = 0; f < 4; ++f) {
            ah[f] = *(const bf16x8*)&P[0][offA[f]];
            al[f] = *(const bf16x8*)&P[1][offA[f]];
            bh[f] = *(const bf16x8*)&P[2][offB[f]];
            bl[f] = *(const bf16x8*)&P[3][offB[f]];
        }
        #pragma unroll
        for (int i = 0; i < 4; ++i)
            #pragma unroll
            for (int j = 0; j < 4; ++j) {
                acc[i][j] = __builtin_amdgcn_mfma_f32_16x16x32_bf16(ah[i], bh[j], acc[i][j], 0, 0, 0);
                acc[i][j] = __builtin_amdgcn_mfma_f32_16x16x32_bf16(ah[i], bl[j], acc[i][j], 0, 0, 0);
                acc[i][j] = __builtin_amdgcn_mfma_f32_16x16x32_bf16(al[i], bh[j], acc[i][j], 0, 0, 0);
            }
        __syncthreads();
    }

    float local = 0.f;
    // pass 1: softplus + direct adj[r][c] (bitmask)
    #pragma unroll
    for (int i = 0; i < 4; ++i) {
        #pragma unroll
        for (int q = 0; q < 4; ++q) {
            int r = rowBase + wm + i * 16 + kg * 4 + q;
            if (r >= N_NODES) continue;
            #pragma unroll
            for (int j = 0; j < 4; ++j) {
                int c = colBase + wn + j * 16 + fr;
                if (c >= N_NODES) continue;
                float z  = acc[i][j][q];
                float sp = fmaxf(z, 0.f) + __logf(1.f + __expf(-fabsf(z)));
                unsigned wd = bits[(long)r * WPR + (c >> 5)];
                float az = ((wd >> (c & 31)) & 1u) ? z : 0.f;
                local += diag ? (sp - az) : (2.f * sp - az);
            }
        }
    }
    // pass 2 (off-diag): adj[c][r] via per-wave fragment transpose
    if (!diag) {
        #pragma unroll
        for (int i = 0; i < 4; ++i) {
            #pragma unroll
            for (int j = 0; j < 4; ++j) {
                #pragma unroll
                for (int q = 0; q < 4; ++q)
                    ztr[w][kg * 4 + q][fr] = acc[i][j][q];
                #pragma unroll
                for (int q = 0; q < 4; ++q) {
                    float zt = ztr[w][fr][kg * 4 + q];
                    int cc = colBase + wn + j * 16 + kg * 4 + q;   // bit row
                    int rr = rowBase + wm + i * 16 + fr;           // bit col
                    if (cc < N_NODES && rr < N_NODES) {
                        unsigned wd = bits[(long)cc * WPR + (rr >> 5)];
                        if ((wd >> (rr & 31)) & 1u) local -= zt;
                    }
                }
            }
        }
    }
    red[t] = local;
    __syncthreads();
    for (int sft = 128; sft > 0; sft >>= 1) {
        if (t < sft) red[t] += red[t + sft];
        __syncthreads();
    }
    if (t == 0) atomicAdd(accum, (double)red[0]);
}

// ---------------- SpMM: wave per (node, 256-ch half); residual from xh/xl ----------------
__global__ void k_spmm(const float* __restrict__ y,
                       const int* __restrict__ rowptr, const int* __restrict__ csrc,
                       const float* __restrict__ cw, const float* __restrict__ bias,
                       int do_relu, short* __restrict__ xh, short* __restrict__ xl)
{
    const int wv   = threadIdx.x >> 6;
    const int lane = threadIdx.x & 63;
    const int n    = blockIdx.x * 2 + (wv >> 1);   // 5808*2 == 11616 exactly
    const int c    = (wv & 1) * 256 + (lane << 2);
    float4 s = make_float4(0.f, 0.f, 0.f, 0.f);
    const int beg = rowptr[n], end = rowptr[n + 1];
    for (int e = beg; e < end; ++e) {
        int   sn = csrc[e];
        float wt = cw[e];
        const float4 yv = *reinterpret_cast<const float4*>(y + (long)sn * NHID + c);
        s.x = fmaf(wt, yv.x, s.x);
        s.y = fmaf(wt, yv.y, s.y);
        s.z = fmaf(wt, yv.z, s.z);
        s.w = fmaf(wt, yv.w, s.w);
    }
    const float4 bv = *reinterpret_cast<const float4*>(bias + c);
    float4 o;
    o.x = s.x + bv.x; o.y = s.y + bv.y; o.z = s.z + bv.z; o.w = s.w + bv.w;
    if (do_relu) {
        o.x = fmaxf(o.x, 0.f); o.y = fmaxf(o.y, 0.f);
        o.z = fmaxf(o.z, 0.f); o.w = fmaxf(o.w, 0.f);
    } else {
        const short4 h4 = *reinterpret_cast<const short4*>(xh + (long)n * NHID + c);
        const short4 l4 = *reinterpret_cast<const short4*>(xl + (long)n * NHID + c);
        o.x += bf2f(h4.x) + bf2f(l4.x);
        o.y += bf2f(h4.y) + bf2f(l4.y);
        o.z += bf2f(h4.z) + bf2f(l4.z);
        o.w += bf2f(h4.w) + bf2f(l4.w);
    }
    short4 h, l;
    split_bf16(o.x, h.x, l.x); split_bf16(o.y, h.y, l.y);
    split_bf16(o.z, h.z, l.z); split_bf16(o.w, h.w, l.w);
    *reinterpret_cast<short4*>(xh + (long)n * NHID + c) = h;
    *reinterpret_cast<short4*>(xl + (long)n * NHID + c) = l;
}

// ---------------- recon loss ----------------
__global__ void k_recon(const float* __restrict__ r0, const float* __restrict__ X0,
                        double* __restrict__ accum)
{
    const int row = blockIdx.x;
    const int t = threadIdx.x;   // 256
    float dot = 0.f, nr = 0.f, nf = 0.f;
    for (int c = t; c < F0; c += 256) {
        float a = r0[(long)row * F0 + c];
        float b = X0[(long)row * F0 + c];
        dot = fmaf(a, b, dot);
        nr  = fmaf(a, a, nr);
        nf  = fmaf(b, b, nf);
    }
    #pragma unroll
    for (int o = 32; o > 0; o >>= 1) {
        dot += __shfl_down(dot, o);
        nr  += __shfl_down(nr, o);
        nf  += __shfl_down(nf, o);
    }
    __shared__ float sd[3][4];
    const int lane = t & 63, wid = t >> 6;
    if (lane == 0) { sd[0][wid] = dot; sd[1][wid] = nr; sd[2][wid] = nf; }
    __syncthreads();
    if (t == 0) {
        float d = sd[0][0] + sd[0][1] + sd[0][2] + sd[0][3];
        float a = sd[1][0] + sd[1][1] + sd[1][2] + sd[1][3];
        float b = sd[2][0] + sd[2][1] + sd[2][2] + sd[2][3];
        float cosv = d / (fmaxf(sqrtf(a), 1e-12f) * fmaxf(sqrtf(b), 1e-12f));
        float v = 1.f - cosv;
        atomicAdd(accum + 1, (double)(v * v * v));
    }
}

__global__ void k_final(const double* __restrict__ accum, float* __restrict__ out)
{
    if (threadIdx.x == 0) {
        out[45082958] = (float)(accum[0] / ((double)N_NODES * (double)N_NODES));
        out[45082959] = (float)(accum[1] / (double)S0);
    }
}

extern "C" void kernel_launch(void* const* d_in, const int* in_sizes, int n_in,
                              void* d_out, int out_size, void* d_ws, size_t ws_size,
                              hipStream_t stream)
{
    const float* X0  = (const float*)d_in[0];
    const float* X1  = (const float*)d_in[1];
    const float* X2  = (const float*)d_in[2];
    const int*   src = (const int*)d_in[3];
    const int*   dst = (const int*)d_in[4];
    const float* ew  = (const float*)d_in[5];
    const float* adj = (const float*)d_in[6];
    const float* fcW[3]  = {(const float*)d_in[7],  (const float*)d_in[9],  (const float*)d_in[11]};
    const float* fcB[3]  = {(const float*)d_in[8],  (const float*)d_in[10], (const float*)d_in[12]};
    const float* encW = (const float*)d_in[13];
    const float* encB = (const float*)d_in[14];
    const float* decW = (const float*)d_in[15];
    const float* decB = (const float*)d_in[16];
    const float* outW[3] = {(const float*)d_in[17], (const float*)d_in[19], (const float*)d_in[21]};
    const float* outB[3] = {(const float*)d_in[18], (const float*)d_in[20], (const float*)d_in[22]};
    float* out = (float*)d_out;

    const int FD[3]     = {F0, F1, F2};
    const int FPAD[3]   = {(F0 + 127) & ~127, (F1 + 127) & ~127, (F2 + 127) & ~127}; // K pad (128-mult)
    const int SPAD[3]   = {(S0 + 127) & ~127, (S1 + 127) & ~127, (S2 + 127) & ~127}; // row pad
    const int SD[3]     = {S0, S1, S2};
    const float* XD[3]  = {X0, X1, X2};

    char* ws = (char*)d_ws;
    size_t off = 0;
    auto alloc = [&](size_t bytes) { void* p = ws + off; off += (bytes + 255) & ~(size_t)255; return p; };

    double* accum = (double*)alloc(16);
    const size_t XB = (size_t)N_NODES * NHID * sizeof(float);
    float* ybuf = (float*)alloc(XB);   // FC phase: aliased as split-K partial buffer (part 1)
    float* xalt = (float*)alloc(XB);   // FC phase: split-K partial buffer (part 2)
    short* xh   = (short*)alloc((size_t)NROWPAD * NHID * 2);
    short* xl   = (short*)alloc((size_t)NROWPAD * NHID * 2);
    // X split staging (max over the 3 types); reused later for outW splits
    const size_t XSmax = (size_t)5376 * 5376;
    short* Xsh  = (short*)alloc(XSmax * 2);
    short* Xsl  = (short*)alloc(XSmax * 2);
    // fc weight split (max 512*5376)
    short* fcWh = (short*)alloc((size_t)NHID * 5376 * 2);
    short* fcWl = (short*)alloc((size_t)NHID * 5376 * 2);
    short* wTh  = (short*)alloc((size_t)8 * NHID * NHID * 2);
    short* wTl  = (short*)alloc((size_t)8 * NHID * NHID * 2);
    unsigned* bits = (unsigned*)alloc((size_t)N_NODES * WPR * 4);   // 16.9 MB
    int* indeg  = (int*)alloc((size_t)N_NODES * 4);
    int* rowptr = (int*)alloc((size_t)(N_NODES + 1) * 4);
    int* cursor = (int*)alloc((size_t)N_NODES * 4);
    int* csrc   = (int*)alloc((size_t)EDGES * 4);
    float* cw   = (float*)alloc((size_t)EDGES * 4);

    float* cpart = ybuf;   // alias: spans ybuf+xalt (free until first layer GEMM)

    // ---- CSR build + pad zero + adj bitmask ----
    k_init<<<dim3((N_NODES + 255) / 256), dim3(256), 0, stream>>>(accum, indeg, cursor);
    k_padzero<<<dim3(((NROWPAD - N_NODES) * NHID + 255) / 256), dim3(256), 0, stream>>>(xh, xl);
    k_count<<<dim3((EDGES + 255) / 256), dim3(256), 0, stream>>>(dst, indeg);
    k_scan<<<dim3(1), dim3(256), 0, stream>>>(indeg, rowptr);
    k_fill<<<dim3((EDGES + 255) / 256), dim3(256), 0, stream>>>(src, dst, ew, rowptr, cursor, csrc, cw);
    {
        long words = (long)N_NODES * WPR;
        k_adjbits<<<dim3((unsigned)((words + 255) / 256)), dim3(256), 0, stream>>>(adj, bits);
    }

    auto tgrid = [](int Cpad, int Rpad) { return dim3((unsigned)((Cpad + 31) / 32), (unsigned)((Rpad + 31) / 32)); };
    auto ggrid = [](int m, int nn) { return dim3((unsigned)((nn + 127) / 128), (unsigned)((m + 127) / 128)); };

    // ---- enc/dec weight transpose+split ----
    for (int i = 0; i < 4; ++i) {
        k_tsplit<<<tgrid(NHID, NHID), dim3(32, 8), 0, stream>>>(
            encW + (size_t)i * NHID * NHID, wTh + (size_t)i * NHID * NHID,
            wTl + (size_t)i * NHID * NHID, NHID, NHID, NHID, NHID);
        k_tsplit<<<tgrid(NHID, NHID), dim3(32, 8), 0, stream>>>(
            decW + (size_t)i * NHID * NHID, wTh + (size_t)(4 + i) * NHID * NHID,
            wTl + (size_t)(4 + i) * NHID * NHID, NHID, NHID, NHID, NHID);
    }

    // ---- input FCs via split-K ----
    {
        size_t rowoff = 0;
        for (int i = 0; i < 3; ++i) {
            k_splitpad<<<dim3((FPAD[i] + 255) / 256, SPAD[i]), dim3(256), 0, stream>>>(
                XD[i], Xsh, Xsl, SD[i], FD[i], FPAD[i]);
            k_tsplit<<<tgrid(NHID, FPAD[i]), dim3(32, 8), 0, stream>>>(
                fcW[i], fcWh, fcWl, FD[i], NHID, FPAD[i], NHID);
            k_gemm_red<<<dim3(NHID / 128, SPAD[i] / 128, FC_KS), dim3(256), 0, stream>>>(
                Xsh, Xsl, fcWh, fcWl, cpart, SD[i], FPAD[i], FPAD[i] / FC_KS);
            k_fcreduce<<<dim3(SD[i]), dim3(128), 0, stream>>>(
                cpart, fcB[i], SD[i], xh + rowoff * NHID, xl + rowoff * NHID);
            rowoff += SD[i];
        }
    }

    // ---- 8 GNN layers (x lives only as xh/xl split pair) ----
    for (int phase = 0; phase < 2; ++phase) {
        const float* B = phase ? decB : encB;
        for (int i = 0; i < 4; ++i) {
            k_gemm_bb<<<ggrid(N_NODES, NHID), dim3(256), 0, stream>>>(
                xh, xl, wTh + (size_t)(phase * 4 + i) * NHID * NHID,
                wTl + (size_t)(phase * 4 + i) * NHID * NHID,
                nullptr, ybuf, N_NODES, NHID, NHID, NHID);
            k_spmm<<<dim3(N_NODES / 2), dim3(256), 0, stream>>>(
                ybuf, rowptr, csrc, cw, B + (size_t)i * NHID, (i == 0) ? 1 : 0,
                xh, xl);
        }
    }

    // ---- outW transpose+split (into the now-free X staging region) ----
    short* oWh = Xsh;
    short* oWl = Xsl;
    {
        short *ph = oWh, *pl = oWl;
        for (int i = 0; i < 3; ++i) {
            int FDP = (FD[i] + 127) & ~127;
            k_tsplit<<<tgrid(FDP, NHID), dim3(32, 8), 0, stream>>>(
                outW[i], ph, pl, NHID, FD[i], NHID, FDP);
            ph += (size_t)FDP * NHID; pl += (size_t)FDP * NHID;
        }
    }

    // ---- output projections ----
    {
        short *ph = oWh, *pl = oWl;
        float* oo = out;
        size_t rowoff = 0;
        for (int i = 0; i < 3; ++i) {
            int FDP = (FD[i] + 127) & ~127;
            k_gemm_bb<<<ggrid(SD[i], FD[i]), dim3(256), 0, stream>>>(
                xh + rowoff * NHID, xl + rowoff * NHID, ph, pl, outB[i], oo,
                SD[i], FD[i], NHID, NHID);
            ph += (size_t)FDP * NHID; pl += (size_t)FDP * NHID;
            oo += (size_t)SD[i] * FD[i];
            rowoff += SD[i];
        }
    }

    // ---- losses ----
    k_zloss<<<dim3(NZBLK), dim3(256), 0, stream>>>(xh, xl, bits, accum);
    k_recon<<<dim3(S0), dim3(256), 0, stream>>>(out, X0, accum);
    k_final<<<dim3(1), dim3(64), 0, stream>>>(accum, out);
}